// Round 1
// baseline (142.120 us; speedup 1.0000x reference)
//
#include <hip/hip_runtime.h>
#include <hip/hip_bf16.h>
#include <math.h>

typedef short bf16x8 __attribute__((ext_vector_type(8)));      // 8 bf16 = 4 VGPRs
typedef float f32x4 __attribute__((ext_vector_type(4)));
typedef float float4v __attribute__((ext_vector_type(4)));
typedef unsigned short ushort4v __attribute__((ext_vector_type(4))); // 8 bytes

static __device__ __forceinline__ float eluf(float x) {
  return x > 0.f ? x : expm1f(x);
}
// round-to-nearest-even f32 -> bf16
static __device__ __forceinline__ unsigned short f2bf(float f) {
  union { float f; unsigned u; } v; v.f = f;
  unsigned r = v.u + 0x7FFFu + ((v.u >> 16) & 1u);
  return (unsigned short)(r >> 16);
}

// ---------------- prologue 1: h = elu(A_flat @ W1^T), h[256] ----------------
__global__ void k_hidden(const float* __restrict__ A, const float* __restrict__ W1,
                         float* __restrict__ hout) {
  int j = blockIdx.x, t = threadIdx.x;
  const float* row = W1 + (size_t)j * 4096;
  float s = 0.f;
  for (int i = t; i < 4096; i += 256) s += A[i] * row[i];
  __shared__ float red[256];
  red[t] = s; __syncthreads();
  for (int off = 128; off > 0; off >>= 1) {
    if (t < off) red[t] += red[t + off];
    __syncthreads();
  }
  if (t == 0) hout[j] = eluf(red[0]);
}

// ---------------- prologue 2: Ad = relu(h @ W2^T); D = rownorm(Ad) as bf16 --
__global__ void k_dinv(const float* __restrict__ hbuf, const float* __restrict__ W2,
                       unsigned short* __restrict__ Dout) {
  int x = blockIdx.x, t = threadIdx.x;
  int lane = t & 63, w = t >> 6;
  __shared__ float hs[256];
  __shared__ float ad[64];
  hs[t] = hbuf[t];
  __syncthreads();
  // wave w computes e = w*16 .. w*16+15
  for (int ei = 0; ei < 16; ++ei) {
    int e = w * 16 + ei;
    const float* row = W2 + (size_t)(x * 64 + e) * 256;
    float p = 0.f;
    for (int q = 0; q < 4; ++q) p += row[q * 64 + lane] * hs[q * 64 + lane];
    for (int off = 32; off > 0; off >>= 1) p += __shfl_down(p, off);
    if (lane == 0) ad[e] = fmaxf(p, 0.f);
  }
  __syncthreads();
  if (t < 64) {
    float v = ad[t];
    float rs = v;
    for (int off = 1; off < 64; off <<= 1) rs += __shfl_xor(rs, off);
    Dout[x * 64 + t] = f2bf(v / fmaxf(rs, 1e-6f));
  }
}

// ---------------- prologue 3: T1T/T2T[g][n][k] = bf16(T[g][k][n]) ----------
__global__ void k_transT(const float* __restrict__ T1, const float* __restrict__ T2,
                         unsigned short* __restrict__ T1T, unsigned short* __restrict__ T2T) {
  int idx = blockIdx.x * 256 + threadIdx.x;   // 0 .. 163839
  const float* src = (idx < 81920) ? T1 : T2;
  unsigned short* dst = (idx < 81920) ? T1T : T2T;
  int o = (idx < 81920) ? idx : idx - 81920;
  int g = o >> 14;
  int r = o & 16383;
  int h = r >> 7;      // out row = n index
  int f = r & 127;     // out col = k index
  dst[o] = f2bf(src[g * 16384 + f * 128 + h]);
}

// ---------------- main: per (g,b): out = elu(D @ elu(mu@T1) @ T2) ----------
// One block per (g,b); 4 waves; wave w owns output cols [32w, 32w+32).
// LDS: mu bf16 [64][128] (swz), h1T bf16 [128][64] (swz), h2 bf16 [64][128] (swz).
__launch_bounds__(256, 3)
__global__ void k_main(const float* __restrict__ mu,
                       const unsigned short* __restrict__ Dm,
                       const unsigned short* __restrict__ T1T,
                       const unsigned short* __restrict__ T2T,
                       float* __restrict__ out) {
  __shared__ __align__(16) char smem[49152];
  char* s_mu = smem;           // 16KB
  char* s_h1 = smem + 16384;   // 16KB
  char* s_h2 = smem + 32768;   // 16KB

  const int g = blockIdx.y, b = blockIdx.x;
  const int t = threadIdx.x;
  const int lane = t & 63, w = t >> 6;
  const int l15 = lane & 15, lk = lane >> 4;
  const int nb = w * 32;

  // ---- stage mu (f32 -> bf16, swizzled) ----
  const float* mub = mu + (size_t)(g * 1024 + b) * 8192;
  #pragma unroll
  for (int k = 0; k < 8; ++k) {
    int q = t + k * 256;                   // float4 index, 2048 total
    float4v v = ((const float4v*)mub)[q];
    int row = q >> 5;
    int col4 = (q & 31) * 4;
    ushort4v u;
    u[0] = f2bf(v[0]); u[1] = f2bf(v[1]); u[2] = f2bf(v[2]); u[3] = f2bf(v[3]);
    int byte = (row * 256 + col4 * 2) ^ ((row & 7) << 4);
    *(ushort4v*)(s_mu + byte) = u;
  }
  __syncthreads();

  // ---- GEMM1: h1 = elu(mu @ T1)  (M=64, N=128, K=128) ----
  f32x4 acc[4][2];
  #pragma unroll
  for (int m = 0; m < 4; ++m)
    #pragma unroll
    for (int n = 0; n < 2; ++n)
      acc[m][n] = (f32x4){0.f, 0.f, 0.f, 0.f};

  const unsigned short* t1g = T1T + g * 16384;
  #pragma unroll
  for (int kc = 0; kc < 4; ++kc) {
    int k0 = kc * 32 + lk * 8;
    bf16x8 b0 = *(const bf16x8*)(const void*)(t1g + (nb + l15) * 128 + k0);
    bf16x8 b1 = *(const bf16x8*)(const void*)(t1g + (nb + 16 + l15) * 128 + k0);
    #pragma unroll
    for (int m = 0; m < 4; ++m) {
      int row = m * 16 + l15;
      int byte = (row * 256 + k0 * 2) ^ ((row & 7) << 4);
      bf16x8 a = *(const bf16x8*)(s_mu + byte);
      acc[m][0] = __builtin_amdgcn_mfma_f32_16x16x32_bf16(a, b0, acc[m][0], 0, 0, 0);
      acc[m][1] = __builtin_amdgcn_mfma_f32_16x16x32_bf16(a, b1, acc[m][1], 0, 0, 0);
    }
  }
  // write h1T[h][e] (elu applied), swizzled; wave-local columns
  #pragma unroll
  for (int m = 0; m < 4; ++m)
    #pragma unroll
    for (int n = 0; n < 2; ++n) {
      int col = nb + n * 16 + l15;           // h
      int e0 = m * 16 + lk * 4;              // e base
      ushort4v u;
      u[0] = f2bf(eluf(acc[m][n][0]));
      u[1] = f2bf(eluf(acc[m][n][1]));
      u[2] = f2bf(eluf(acc[m][n][2]));
      u[3] = f2bf(eluf(acc[m][n][3]));
      int byte = (col * 128 + e0 * 2) ^ ((col & 7) << 4);
      *(ushort4v*)(s_h1 + byte) = u;
    }
  __syncthreads();

  // ---- GEMM2: h2 = D @ h1  (M=64, N=128, K=64) ----
  f32x4 acc2[4][2];
  #pragma unroll
  for (int m = 0; m < 4; ++m)
    #pragma unroll
    for (int n = 0; n < 2; ++n)
      acc2[m][n] = (f32x4){0.f, 0.f, 0.f, 0.f};

  #pragma unroll
  for (int kc = 0; kc < 2; ++kc) {
    int k0 = kc * 32 + lk * 8;               // e (K dim)
    int c0 = nb + l15, c1 = nb + 16 + l15;   // h (N dim)
    bf16x8 b0 = *(const bf16x8*)(s_h1 + ((c0 * 128 + k0 * 2) ^ ((c0 & 7) << 4)));
    bf16x8 b1 = *(const bf16x8*)(s_h1 + ((c1 * 128 + k0 * 2) ^ ((c1 & 7) << 4)));
    #pragma unroll
    for (int m = 0; m < 4; ++m) {
      int row = m * 16 + l15;                // x
      bf16x8 aD = *(const bf16x8*)(const void*)(Dm + row * 64 + k0);
      acc2[m][0] = __builtin_amdgcn_mfma_f32_16x16x32_bf16(aD, b0, acc2[m][0], 0, 0, 0);
      acc2[m][1] = __builtin_amdgcn_mfma_f32_16x16x32_bf16(aD, b1, acc2[m][1], 0, 0, 0);
    }
  }
  // scatter h2[x][h] (no activation), swizzled, 2B writes
  #pragma unroll
  for (int m = 0; m < 4; ++m)
    #pragma unroll
    for (int n = 0; n < 2; ++n) {
      int hc = nb + n * 16 + l15;
      #pragma unroll
      for (int r = 0; r < 4; ++r) {
        int x = m * 16 + lk * 4 + r;
        int byte = (x * 256 + hc * 2) ^ ((x & 7) << 4);
        *(unsigned short*)(s_h2 + byte) = f2bf(acc2[m][n][r]);
      }
    }
  __syncthreads();

  // ---- GEMM3: out = elu(h2 @ T2)  (M=64, N=128, K=128) ----
  f32x4 acc3[4][2];
  #pragma unroll
  for (int m = 0; m < 4; ++m)
    #pragma unroll
    for (int n = 0; n < 2; ++n)
      acc3[m][n] = (f32x4){0.f, 0.f, 0.f, 0.f};

  const unsigned short* t2g = T2T + g * 16384;
  #pragma unroll
  for (int kc = 0; kc < 4; ++kc) {
    int k0 = kc * 32 + lk * 8;
    bf16x8 b0 = *(const bf16x8*)(const void*)(t2g + (nb + l15) * 128 + k0);
    bf16x8 b1 = *(const bf16x8*)(const void*)(t2g + (nb + 16 + l15) * 128 + k0);
    #pragma unroll
    for (int m = 0; m < 4; ++m) {
      int row = m * 16 + l15;
      int byte = (row * 256 + k0 * 2) ^ ((row & 7) << 4);
      bf16x8 a = *(const bf16x8*)(s_h2 + byte);
      acc3[m][0] = __builtin_amdgcn_mfma_f32_16x16x32_bf16(a, b0, acc3[m][0], 0, 0, 0);
      acc3[m][1] = __builtin_amdgcn_mfma_f32_16x16x32_bf16(a, b1, acc3[m][1], 0, 0, 0);
    }
  }
  float* ob = out + (size_t)(g * 1024 + b) * 8192;
  #pragma unroll
  for (int m = 0; m < 4; ++m)
    #pragma unroll
    for (int n = 0; n < 2; ++n) {
      int f = nb + n * 16 + l15;
      #pragma unroll
      for (int r = 0; r < 4; ++r) {
        int e = m * 16 + lk * 4 + r;
        ob[e * 128 + f] = eluf(acc3[m][n][r]);
      }
    }
}

extern "C" void kernel_launch(void* const* d_in, const int* in_sizes, int n_in,
                              void* d_out, int out_size, void* d_ws, size_t ws_size,
                              hipStream_t stream) {
  const float* mu = (const float*)d_in[0];
  const float* A  = (const float*)d_in[1];
  const float* W1 = (const float*)d_in[2];
  const float* W2 = (const float*)d_in[3];
  const float* T1 = (const float*)d_in[4];
  const float* T2 = (const float*)d_in[5];
  float* out = (float*)d_out;

  char* ws = (char*)d_ws;
  float* hbuf          = (float*)ws;                     // 1 KB
  unsigned short* Dm   = (unsigned short*)(ws + 1024);   // 8 KB
  unsigned short* T1T  = (unsigned short*)(ws + 9216);   // 160 KB
  unsigned short* T2T  = (unsigned short*)(ws + 173056); // 160 KB

  hipLaunchKernelGGL(k_hidden, dim3(256), dim3(256), 0, stream, A, W1, hbuf);
  hipLaunchKernelGGL(k_dinv,   dim3(64),  dim3(256), 0, stream, hbuf, W2, Dm);
  hipLaunchKernelGGL(k_transT, dim3(640), dim3(256), 0, stream, T1, T2, T1T, T2T);
  hipLaunchKernelGGL(k_main,   dim3(1024, 5), dim3(256), 0, stream, mu, Dm, T1T, T2T, out);
}

// Round 2
// 123.331 us; speedup vs baseline: 1.1523x; 1.1523x over previous
//
#include <hip/hip_runtime.h>
#include <hip/hip_bf16.h>
#include <math.h>

typedef short bf16x8 __attribute__((ext_vector_type(8)));      // 8 bf16 = 4 VGPRs
typedef float f32x4 __attribute__((ext_vector_type(4)));
typedef float float4v __attribute__((ext_vector_type(4)));
typedef unsigned short ushort4v __attribute__((ext_vector_type(4))); // 8 bytes

// cheap elu: exp(x)-1 via hardware v_exp_f32 (error ~1e-7 abs, threshold 3.4e-4)
static __device__ __forceinline__ float eluf(float x) {
  float e = __expf(x) - 1.0f;
  return x > 0.f ? x : e;
}
// f32 -> bf16 via HIP cast so compiler can fuse pairs into v_cvt_pk_bf16_f32
static __device__ __forceinline__ unsigned short f2bf(float f) {
  __hip_bfloat16 h = __float2bfloat16(f);
  return *reinterpret_cast<unsigned short*>(&h);
}
// precise RNE for the tiny prologues (D matrix feeds all outputs; keep exact)
static __device__ __forceinline__ unsigned short f2bf_rne(float f) {
  union { float f; unsigned u; } v; v.f = f;
  unsigned r = v.u + 0x7FFFu + ((v.u >> 16) & 1u);
  return (unsigned short)(r >> 16);
}

// ---------------- prologue 1: h = elu(A_flat @ W1^T), h[256] ----------------
__global__ void k_hidden(const float* __restrict__ A, const float* __restrict__ W1,
                         float* __restrict__ hout) {
  int j = blockIdx.x, t = threadIdx.x;
  const float* row = W1 + (size_t)j * 4096;
  float s = 0.f;
  for (int i = t; i < 4096; i += 256) s += A[i] * row[i];
  __shared__ float red[256];
  red[t] = s; __syncthreads();
  for (int off = 128; off > 0; off >>= 1) {
    if (t < off) red[t] += red[t + off];
    __syncthreads();
  }
  if (t == 0) {
    float x = red[0];
    hout[j] = x > 0.f ? x : expm1f(x);   // prologue: keep precise
  }
}

// ---------------- prologue 2: Ad = relu(h @ W2^T); D = rownorm(Ad) as bf16 --
__global__ void k_dinv(const float* __restrict__ hbuf, const float* __restrict__ W2,
                       unsigned short* __restrict__ Dout) {
  int x = blockIdx.x, t = threadIdx.x;
  int lane = t & 63, w = t >> 6;
  __shared__ float hs[256];
  __shared__ float ad[64];
  hs[t] = hbuf[t];
  __syncthreads();
  for (int ei = 0; ei < 16; ++ei) {
    int e = w * 16 + ei;
    const float* row = W2 + (size_t)(x * 64 + e) * 256;
    float p = 0.f;
    for (int q = 0; q < 4; ++q) p += row[q * 64 + lane] * hs[q * 64 + lane];
    for (int off = 32; off > 0; off >>= 1) p += __shfl_down(p, off);
    if (lane == 0) ad[e] = fmaxf(p, 0.f);
  }
  __syncthreads();
  if (t < 64) {
    float v = ad[t];
    float rs = v;
    for (int off = 1; off < 64; off <<= 1) rs += __shfl_xor(rs, off);
    Dout[x * 64 + t] = f2bf_rne(v / fmaxf(rs, 1e-6f));
  }
}

// ---------------- prologue 3: T1T/T2T[g][n][k] = bf16(T[g][k][n]) ----------
__global__ void k_transT(const float* __restrict__ T1, const float* __restrict__ T2,
                         unsigned short* __restrict__ T1T, unsigned short* __restrict__ T2T) {
  int idx = blockIdx.x * 256 + threadIdx.x;   // 0 .. 163839
  const float* src = (idx < 81920) ? T1 : T2;
  unsigned short* dst = (idx < 81920) ? T1T : T2T;
  int o = (idx < 81920) ? idx : idx - 81920;
  int g = o >> 14;
  int r = o & 16383;
  int h = r >> 7;      // out row = n index
  int f = r & 127;     // out col = k index
  dst[o] = f2bf_rne(src[g * 16384 + f * 128 + h]);
}

// ---------------- main: per (g,b): out = elu(D @ elu(mu@T1) @ T2) ----------
// One block per (g,b); 4 waves; wave w owns output cols [32w, 32w+32).
// LDS (32 KB -> 5 blocks/CU): s_mu [64][128]bf16 swz, aliased by s_h2 after
// GEMM1 (the post-h1 barrier dominates the last s_mu read); s_h1 [128][64] swz.
__launch_bounds__(256, 5)
__global__ void k_main(const float* __restrict__ mu,
                       const unsigned short* __restrict__ Dm,
                       const unsigned short* __restrict__ T1T,
                       const unsigned short* __restrict__ T2T,
                       float* __restrict__ out) {
  __shared__ __align__(16) char smem[32768];
  char* s_mu = smem;           // 16KB; reused as s_h2 after GEMM1
  char* s_h1 = smem + 16384;   // 16KB
  char* s_h2 = smem;           // alias

  const int g = blockIdx.y, b = blockIdx.x;
  const int t = threadIdx.x;
  const int lane = t & 63, w = t >> 6;
  const int l15 = lane & 15, lk = lane >> 4;
  const int nb = w * 32;

  // ---- stage mu (f32 -> bf16, swizzled) ----
  const float* mub = mu + (size_t)(g * 1024 + b) * 8192;
  #pragma unroll
  for (int k = 0; k < 8; ++k) {
    int q = t + k * 256;                   // float4 index, 2048 total
    float4v v = ((const float4v*)mub)[q];
    int row = q >> 5;
    int col4 = (q & 31) * 4;
    ushort4v u;
    u[0] = f2bf(v[0]); u[1] = f2bf(v[1]); u[2] = f2bf(v[2]); u[3] = f2bf(v[3]);
    int byte = (row * 256 + col4 * 2) ^ ((row & 7) << 4);
    *(ushort4v*)(s_mu + byte) = u;
  }
  __syncthreads();

  // ---- GEMM1: h1 = elu(mu @ T1)  (M=64, N=128, K=128) ----
  f32x4 acc[4][2];
  #pragma unroll
  for (int m = 0; m < 4; ++m)
    #pragma unroll
    for (int n = 0; n < 2; ++n)
      acc[m][n] = (f32x4){0.f, 0.f, 0.f, 0.f};

  const unsigned short* t1g = T1T + g * 16384;
  #pragma unroll
  for (int kc = 0; kc < 4; ++kc) {
    int k0 = kc * 32 + lk * 8;
    bf16x8 b0 = *(const bf16x8*)(const void*)(t1g + (nb + l15) * 128 + k0);
    bf16x8 b1 = *(const bf16x8*)(const void*)(t1g + (nb + 16 + l15) * 128 + k0);
    #pragma unroll
    for (int m = 0; m < 4; ++m) {
      int row = m * 16 + l15;
      int byte = (row * 256 + k0 * 2) ^ ((row & 7) << 4);
      bf16x8 a = *(const bf16x8*)(s_mu + byte);
      acc[m][0] = __builtin_amdgcn_mfma_f32_16x16x32_bf16(a, b0, acc[m][0], 0, 0, 0);
      acc[m][1] = __builtin_amdgcn_mfma_f32_16x16x32_bf16(a, b1, acc[m][1], 0, 0, 0);
    }
  }
  // write h1T[h][e] (elu applied), swizzled; wave-local columns
  #pragma unroll
  for (int m = 0; m < 4; ++m)
    #pragma unroll
    for (int n = 0; n < 2; ++n) {
      int col = nb + n * 16 + l15;           // h
      int e0 = m * 16 + lk * 4;              // e base
      ushort4v u;
      u[0] = f2bf(eluf(acc[m][n][0]));
      u[1] = f2bf(eluf(acc[m][n][1]));
      u[2] = f2bf(eluf(acc[m][n][2]));
      u[3] = f2bf(eluf(acc[m][n][3]));
      int byte = (col * 128 + e0 * 2) ^ ((col & 7) << 4);
      *(ushort4v*)(s_h1 + byte) = u;
    }
  __syncthreads();   // all GEMM1 s_mu reads done; s_h2 may now overwrite it

  // ---- GEMM2: h2 = D @ h1  (M=64, N=128, K=64) ----
  f32x4 acc2[4][2];
  #pragma unroll
  for (int m = 0; m < 4; ++m)
    #pragma unroll
    for (int n = 0; n < 2; ++n)
      acc2[m][n] = (f32x4){0.f, 0.f, 0.f, 0.f};

  #pragma unroll
  for (int kc = 0; kc < 2; ++kc) {
    int k0 = kc * 32 + lk * 8;               // e (K dim)
    int c0 = nb + l15, c1 = nb + 16 + l15;   // h (N dim)
    bf16x8 b0 = *(const bf16x8*)(s_h1 + ((c0 * 128 + k0 * 2) ^ ((c0 & 7) << 4)));
    bf16x8 b1 = *(const bf16x8*)(s_h1 + ((c1 * 128 + k0 * 2) ^ ((c1 & 7) << 4)));
    #pragma unroll
    for (int m = 0; m < 4; ++m) {
      int row = m * 16 + l15;                // x
      bf16x8 aD = *(const bf16x8*)(const void*)(Dm + row * 64 + k0);
      acc2[m][0] = __builtin_amdgcn_mfma_f32_16x16x32_bf16(aD, b0, acc2[m][0], 0, 0, 0);
      acc2[m][1] = __builtin_amdgcn_mfma_f32_16x16x32_bf16(aD, b1, acc2[m][1], 0, 0, 0);
    }
  }
  // scatter h2[x][h] (no activation), swizzled, 2B writes
  #pragma unroll
  for (int m = 0; m < 4; ++m)
    #pragma unroll
    for (int n = 0; n < 2; ++n) {
      int hc = nb + n * 16 + l15;
      #pragma unroll
      for (int r = 0; r < 4; ++r) {
        int x = m * 16 + lk * 4 + r;
        int byte = (x * 256 + hc * 2) ^ ((x & 7) << 4);
        *(unsigned short*)(s_h2 + byte) = f2bf(acc2[m][n][r]);
      }
    }
  __syncthreads();

  // ---- GEMM3: out = elu(h2 @ T2)  (M=64, N=128, K=128) ----
  f32x4 acc3[4][2];
  #pragma unroll
  for (int m = 0; m < 4; ++m)
    #pragma unroll
    for (int n = 0; n < 2; ++n)
      acc3[m][n] = (f32x4){0.f, 0.f, 0.f, 0.f};

  const unsigned short* t2g = T2T + g * 16384;
  #pragma unroll
  for (int kc = 0; kc < 4; ++kc) {
    int k0 = kc * 32 + lk * 8;
    bf16x8 b0 = *(const bf16x8*)(const void*)(t2g + (nb + l15) * 128 + k0);
    bf16x8 b1 = *(const bf16x8*)(const void*)(t2g + (nb + 16 + l15) * 128 + k0);
    #pragma unroll
    for (int m = 0; m < 4; ++m) {
      int row = m * 16 + l15;
      int byte = (row * 256 + k0 * 2) ^ ((row & 7) << 4);
      bf16x8 a = *(const bf16x8*)(s_h2 + byte);
      acc3[m][0] = __builtin_amdgcn_mfma_f32_16x16x32_bf16(a, b0, acc3[m][0], 0, 0, 0);
      acc3[m][1] = __builtin_amdgcn_mfma_f32_16x16x32_bf16(a, b1, acc3[m][1], 0, 0, 0);
    }
  }
  float* ob = out + (size_t)(g * 1024 + b) * 8192;
  #pragma unroll
  for (int m = 0; m < 4; ++m)
    #pragma unroll
    for (int n = 0; n < 2; ++n) {
      int f = nb + n * 16 + l15;
      #pragma unroll
      for (int r = 0; r < 4; ++r) {
        int e = m * 16 + lk * 4 + r;
        ob[e * 128 + f] = eluf(acc3[m][n][r]);
      }
    }
}

extern "C" void kernel_launch(void* const* d_in, const int* in_sizes, int n_in,
                              void* d_out, int out_size, void* d_ws, size_t ws_size,
                              hipStream_t stream) {
  const float* mu = (const float*)d_in[0];
  const float* A  = (const float*)d_in[1];
  const float* W1 = (const float*)d_in[2];
  const float* W2 = (const float*)d_in[3];
  const float* T1 = (const float*)d_in[4];
  const float* T2 = (const float*)d_in[5];
  float* out = (float*)d_out;

  char* ws = (char*)d_ws;
  float* hbuf          = (float*)ws;                     // 1 KB
  unsigned short* Dm   = (unsigned short*)(ws + 1024);   // 8 KB
  unsigned short* T1T  = (unsigned short*)(ws + 9216);   // 160 KB
  unsigned short* T2T  = (unsigned short*)(ws + 173056); // 160 KB

  hipLaunchKernelGGL(k_hidden, dim3(256), dim3(256), 0, stream, A, W1, hbuf);
  hipLaunchKernelGGL(k_dinv,   dim3(64),  dim3(256), 0, stream, hbuf, W2, Dm);
  hipLaunchKernelGGL(k_transT, dim3(640), dim3(256), 0, stream, T1, T2, T1T, T2T);
  hipLaunchKernelGGL(k_main,   dim3(1024, 5), dim3(256), 0, stream, mu, Dm, T1T, T2T, out);
}

// Round 3
// 122.301 us; speedup vs baseline: 1.1620x; 1.0084x over previous
//
#include <hip/hip_runtime.h>
#include <hip/hip_bf16.h>
#include <math.h>

typedef short bf16x8 __attribute__((ext_vector_type(8)));      // 8 bf16 = 4 VGPRs
typedef float f32x4 __attribute__((ext_vector_type(4)));
typedef float float4v __attribute__((ext_vector_type(4)));
typedef unsigned short ushort4v __attribute__((ext_vector_type(4))); // 8 bytes

// cheap elu: exp(x)-1 via hardware v_exp_f32 (error ~1e-7 abs, threshold 3.4e-4)
static __device__ __forceinline__ float eluf(float x) {
  float e = __expf(x) - 1.0f;
  return x > 0.f ? x : e;
}
static __device__ __forceinline__ unsigned short f2bf(float f) {
  __hip_bfloat16 h = __float2bfloat16(f);
  return *reinterpret_cast<unsigned short*>(&h);
}
static __device__ __forceinline__ unsigned short f2bf_rne(float f) {
  union { float f; unsigned u; } v; v.f = f;
  unsigned r = v.u + 0x7FFFu + ((v.u >> 16) & 1u);
  return (unsigned short)(r >> 16);
}

// ---------------- prologue 1: h = elu(A_flat @ W1^T), h[256] ----------------
__global__ void k_hidden(const float* __restrict__ A, const float* __restrict__ W1,
                         float* __restrict__ hout) {
  int j = blockIdx.x, t = threadIdx.x;
  const float* row = W1 + (size_t)j * 4096;
  float s = 0.f;
  for (int i = t; i < 4096; i += 256) s += A[i] * row[i];
  __shared__ float red[256];
  red[t] = s; __syncthreads();
  for (int off = 128; off > 0; off >>= 1) {
    if (t < off) red[t] += red[t + off];
    __syncthreads();
  }
  if (t == 0) {
    float x = red[0];
    hout[j] = x > 0.f ? x : expm1f(x);   // prologue: keep precise
  }
}

// ---------------- prologue 2: Ad = relu(h @ W2^T); D = rownorm(Ad) as bf16 --
__global__ void k_dinv(const float* __restrict__ hbuf, const float* __restrict__ W2,
                       unsigned short* __restrict__ Dout) {
  int x = blockIdx.x, t = threadIdx.x;
  int lane = t & 63, w = t >> 6;
  __shared__ float hs[256];
  __shared__ float ad[64];
  hs[t] = hbuf[t];
  __syncthreads();
  for (int ei = 0; ei < 16; ++ei) {
    int e = w * 16 + ei;
    const float* row = W2 + (size_t)(x * 64 + e) * 256;
    float p = 0.f;
    for (int q = 0; q < 4; ++q) p += row[q * 64 + lane] * hs[q * 64 + lane];
    for (int off = 32; off > 0; off >>= 1) p += __shfl_down(p, off);
    if (lane == 0) ad[e] = fmaxf(p, 0.f);
  }
  __syncthreads();
  if (t < 64) {
    float v = ad[t];
    float rs = v;
    for (int off = 1; off < 64; off <<= 1) rs += __shfl_xor(rs, off);
    Dout[x * 64 + t] = f2bf_rne(v / fmaxf(rs, 1e-6f));
  }
}

// ---------------- prologue 3: T1T/T2T[g][n][k] = bf16(T[g][k][n]) ----------
__global__ void k_transT(const float* __restrict__ T1, const float* __restrict__ T2,
                         unsigned short* __restrict__ T1T, unsigned short* __restrict__ T2T) {
  int idx = blockIdx.x * 256 + threadIdx.x;   // 0 .. 163839
  const float* src = (idx < 81920) ? T1 : T2;
  unsigned short* dst = (idx < 81920) ? T1T : T2T;
  int o = (idx < 81920) ? idx : idx - 81920;
  int g = o >> 14;
  int r = o & 16383;
  int h = r >> 7;      // out row = n index
  int f = r & 127;     // out col = k index
  dst[o] = f2bf_rne(src[g * 16384 + f * 128 + h]);
}

// ---------------- main: per (g,b): out = elu(D @ elu(mu@T1) @ T2) ----------
// One block per (g,b); 4 waves; wave w owns output cols [32w, 32w+32).
// ILP strategy: batch-issue ALL global loads for a phase into register arrays
// (mu 8xfloat4, T1 frags, D frags at top; T2 frags after GEMM1) so HBM/L2
// latency is paid once, not per-load. __launch_bounds__(256,3) gives the
// allocator room (~168 VGPR) to keep them in flight.
__launch_bounds__(256, 3)
__global__ void k_main(const float* __restrict__ mu,
                       const unsigned short* __restrict__ Dm,
                       const unsigned short* __restrict__ T1T,
                       const unsigned short* __restrict__ T2T,
                       float* __restrict__ out) {
  __shared__ __align__(16) char smem[32768];
  char* s_mu = smem;           // 16KB; reused as s_h2 after GEMM1
  char* s_h1 = smem + 16384;   // 16KB
  char* s_h2 = smem;           // alias

  const int g = blockIdx.y, b = blockIdx.x;
  const int t = threadIdx.x;
  const int lane = t & 63, w = t >> 6;
  const int l15 = lane & 15, lk = lane >> 4;
  const int nb = w * 32;

  // ---- issue ALL independent global loads up front ----
  const float* mub = mu + (size_t)(g * 1024 + b) * 8192;
  float4v v[8];
  #pragma unroll
  for (int k = 0; k < 8; ++k) v[k] = ((const float4v*)mub)[t + k * 256];

  const unsigned short* t1g = T1T + g * 16384;
  bf16x8 tb0[4], tb1[4];
  #pragma unroll
  for (int kc = 0; kc < 4; ++kc) {
    int k0 = kc * 32 + lk * 8;
    tb0[kc] = *(const bf16x8*)(const void*)(t1g + (nb + l15) * 128 + k0);
    tb1[kc] = *(const bf16x8*)(const void*)(t1g + (nb + 16 + l15) * 128 + k0);
  }
  bf16x8 aDf[4][2];
  #pragma unroll
  for (int m = 0; m < 4; ++m)
    #pragma unroll
    for (int kc = 0; kc < 2; ++kc)
      aDf[m][kc] = *(const bf16x8*)(const void*)(Dm + (m * 16 + l15) * 64 + kc * 32 + lk * 8);

  // ---- stage mu (f32 -> bf16, swizzled) ----
  #pragma unroll
  for (int k = 0; k < 8; ++k) {
    int q = t + k * 256;                   // float4 index, 2048 total
    int row = q >> 5;
    int col4 = (q & 31) * 4;
    ushort4v u;
    u[0] = f2bf(v[k][0]); u[1] = f2bf(v[k][1]); u[2] = f2bf(v[k][2]); u[3] = f2bf(v[k][3]);
    int byte = (row * 256 + col4 * 2) ^ ((row & 7) << 4);
    *(ushort4v*)(s_mu + byte) = u;
  }
  __syncthreads();

  // ---- GEMM1: h1 = elu(mu @ T1)  (M=64, N=128, K=128) ----
  f32x4 acc[4][2];
  #pragma unroll
  for (int m = 0; m < 4; ++m)
    #pragma unroll
    for (int n = 0; n < 2; ++n)
      acc[m][n] = (f32x4){0.f, 0.f, 0.f, 0.f};

  #pragma unroll
  for (int kc = 0; kc < 4; ++kc) {
    int k0 = kc * 32 + lk * 8;
    #pragma unroll
    for (int m = 0; m < 4; ++m) {
      int row = m * 16 + l15;
      int byte = (row * 256 + k0 * 2) ^ ((row & 7) << 4);
      bf16x8 a = *(const bf16x8*)(s_mu + byte);
      acc[m][0] = __builtin_amdgcn_mfma_f32_16x16x32_bf16(a, tb0[kc], acc[m][0], 0, 0, 0);
      acc[m][1] = __builtin_amdgcn_mfma_f32_16x16x32_bf16(a, tb1[kc], acc[m][1], 0, 0, 0);
    }
  }
  // issue T2 fragment loads now — overlap their L2 latency with GEMM2
  const unsigned short* t2g = T2T + g * 16384;
  bf16x8 t2b0[4], t2b1[4];
  #pragma unroll
  for (int kc = 0; kc < 4; ++kc) {
    int k0 = kc * 32 + lk * 8;
    t2b0[kc] = *(const bf16x8*)(const void*)(t2g + (nb + l15) * 128 + k0);
    t2b1[kc] = *(const bf16x8*)(const void*)(t2g + (nb + 16 + l15) * 128 + k0);
  }
  // write h1T[h][e] (elu applied), swizzled; wave-local columns
  #pragma unroll
  for (int m = 0; m < 4; ++m)
    #pragma unroll
    for (int n = 0; n < 2; ++n) {
      int col = nb + n * 16 + l15;           // h
      int e0 = m * 16 + lk * 4;              // e base
      ushort4v u;
      u[0] = f2bf(eluf(acc[m][n][0]));
      u[1] = f2bf(eluf(acc[m][n][1]));
      u[2] = f2bf(eluf(acc[m][n][2]));
      u[3] = f2bf(eluf(acc[m][n][3]));
      int byte = (col * 128 + e0 * 2) ^ ((col & 7) << 4);
      *(ushort4v*)(s_h1 + byte) = u;
    }
  __syncthreads();   // all GEMM1 s_mu reads done; s_h2 may now overwrite it

  // ---- GEMM2: h2 = D @ h1  (M=64, N=128, K=64) ----
  f32x4 acc2[4][2];
  #pragma unroll
  for (int m = 0; m < 4; ++m)
    #pragma unroll
    for (int n = 0; n < 2; ++n)
      acc2[m][n] = (f32x4){0.f, 0.f, 0.f, 0.f};

  #pragma unroll
  for (int kc = 0; kc < 2; ++kc) {
    int k0 = kc * 32 + lk * 8;               // e (K dim)
    int c0 = nb + l15, c1 = nb + 16 + l15;   // h (N dim)
    bf16x8 b0 = *(const bf16x8*)(s_h1 + ((c0 * 128 + k0 * 2) ^ ((c0 & 7) << 4)));
    bf16x8 b1 = *(const bf16x8*)(s_h1 + ((c1 * 128 + k0 * 2) ^ ((c1 & 7) << 4)));
    #pragma unroll
    for (int m = 0; m < 4; ++m) {
      acc2[m][0] = __builtin_amdgcn_mfma_f32_16x16x32_bf16(aDf[m][kc], b0, acc2[m][0], 0, 0, 0);
      acc2[m][1] = __builtin_amdgcn_mfma_f32_16x16x32_bf16(aDf[m][kc], b1, acc2[m][1], 0, 0, 0);
    }
  }
  // scatter h2[x][h] (no activation), swizzled, 2B writes
  #pragma unroll
  for (int m = 0; m < 4; ++m)
    #pragma unroll
    for (int n = 0; n < 2; ++n) {
      int hc = nb + n * 16 + l15;
      #pragma unroll
      for (int r = 0; r < 4; ++r) {
        int x = m * 16 + lk * 4 + r;
        int byte = (x * 256 + hc * 2) ^ ((x & 7) << 4);
        *(unsigned short*)(s_h2 + byte) = f2bf(acc2[m][n][r]);
      }
    }
  __syncthreads();

  // ---- GEMM3: out = elu(h2 @ T2)  (M=64, N=128, K=128) ----
  f32x4 acc3[4][2];
  #pragma unroll
  for (int m = 0; m < 4; ++m)
    #pragma unroll
    for (int n = 0; n < 2; ++n)
      acc3[m][n] = (f32x4){0.f, 0.f, 0.f, 0.f};

  #pragma unroll
  for (int kc = 0; kc < 4; ++kc) {
    int k0 = kc * 32 + lk * 8;
    #pragma unroll
    for (int m = 0; m < 4; ++m) {
      int row = m * 16 + l15;
      int byte = (row * 256 + k0 * 2) ^ ((row & 7) << 4);
      bf16x8 a = *(const bf16x8*)(s_h2 + byte);
      acc3[m][0] = __builtin_amdgcn_mfma_f32_16x16x32_bf16(a, t2b0[kc], acc3[m][0], 0, 0, 0);
      acc3[m][1] = __builtin_amdgcn_mfma_f32_16x16x32_bf16(a, t2b1[kc], acc3[m][1], 0, 0, 0);
    }
  }
  float* ob = out + (size_t)(g * 1024 + b) * 8192;
  #pragma unroll
  for (int m = 0; m < 4; ++m)
    #pragma unroll
    for (int n = 0; n < 2; ++n) {
      int f = nb + n * 16 + l15;
      #pragma unroll
      for (int r = 0; r < 4; ++r) {
        int e = m * 16 + lk * 4 + r;
        ob[e * 128 + f] = eluf(acc3[m][n][r]);
      }
    }
}

extern "C" void kernel_launch(void* const* d_in, const int* in_sizes, int n_in,
                              void* d_out, int out_size, void* d_ws, size_t ws_size,
                              hipStream_t stream) {
  const float* mu = (const float*)d_in[0];
  const float* A  = (const float*)d_in[1];
  const float* W1 = (const float*)d_in[2];
  const float* W2 = (const float*)d_in[3];
  const float* T1 = (const float*)d_in[4];
  const float* T2 = (const float*)d_in[5];
  float* out = (float*)d_out;

  char* ws = (char*)d_ws;
  float* hbuf          = (float*)ws;                     // 1 KB
  unsigned short* Dm   = (unsigned short*)(ws + 1024);   // 8 KB
  unsigned short* T1T  = (unsigned short*)(ws + 9216);   // 160 KB
  unsigned short* T2T  = (unsigned short*)(ws + 173056); // 160 KB

  hipLaunchKernelGGL(k_hidden, dim3(256), dim3(256), 0, stream, A, W1, hbuf);
  hipLaunchKernelGGL(k_dinv,   dim3(64),  dim3(256), 0, stream, hbuf, W2, Dm);
  hipLaunchKernelGGL(k_transT, dim3(640), dim3(256), 0, stream, T1, T2, T1T, T2T);
  hipLaunchKernelGGL(k_main,   dim3(1024, 5), dim3(256), 0, stream, mu, Dm, T1T, T2T, out);
}

// Round 4
// 101.545 us; speedup vs baseline: 1.3996x; 1.2044x over previous
//
#include <hip/hip_runtime.h>
#include <hip/hip_bf16.h>
#include <math.h>

typedef short bf16x8 __attribute__((ext_vector_type(8)));      // 8 bf16 = 4 VGPRs
typedef float f32x4 __attribute__((ext_vector_type(4)));
typedef float float4v __attribute__((ext_vector_type(4)));
typedef unsigned short ushort4v __attribute__((ext_vector_type(4))); // 8 bytes

// cheap elu: exp(x)-1 via hardware v_exp_f32 (error ~1e-7 abs, threshold 3.4e-4)
static __device__ __forceinline__ float eluf(float x) {
  float e = __expf(x) - 1.0f;
  return x > 0.f ? x : e;
}
static __device__ __forceinline__ unsigned short f2bf(float f) {
  __hip_bfloat16 h = __float2bfloat16(f);
  return *reinterpret_cast<unsigned short*>(&h);
}
static __device__ __forceinline__ unsigned short f2bf_rne(float f) {
  union { float f; unsigned u; } v; v.f = f;
  unsigned r = v.u + 0x7FFFu + ((v.u >> 16) & 1u);
  return (unsigned short)(r >> 16);
}

// ---------------- prologue 1: h = elu(A_flat @ W1^T), h[256] ----------------
__global__ void k_hidden(const float* __restrict__ A, const float* __restrict__ W1,
                         float* __restrict__ hout) {
  int j = blockIdx.x, t = threadIdx.x;
  const float* row = W1 + (size_t)j * 4096;
  float s = 0.f;
  for (int i = t; i < 4096; i += 256) s += A[i] * row[i];
  __shared__ float red[256];
  red[t] = s; __syncthreads();
  for (int off = 128; off > 0; off >>= 1) {
    if (t < off) red[t] += red[t + off];
    __syncthreads();
  }
  if (t == 0) {
    float x = red[0];
    hout[j] = x > 0.f ? x : expm1f(x);   // prologue: keep precise
  }
}

// -------- prologue 2 (fused): blocks 0-63 = D rownorm; blocks 64+ = T-transpose
__global__ void k_pre2(const float* __restrict__ hbuf, const float* __restrict__ W2,
                       unsigned short* __restrict__ Dout,
                       const float* __restrict__ T1, const float* __restrict__ T2,
                       unsigned short* __restrict__ T1T, unsigned short* __restrict__ T2T) {
  int t = threadIdx.x;
  if (blockIdx.x < 64) {
    int x = blockIdx.x;
    int lane = t & 63, w = t >> 6;
    __shared__ float hs[256];
    __shared__ float ad[64];
    hs[t] = hbuf[t];
    __syncthreads();
    for (int ei = 0; ei < 16; ++ei) {
      int e = w * 16 + ei;
      const float* row = W2 + (size_t)(x * 64 + e) * 256;
      float p = 0.f;
      for (int q = 0; q < 4; ++q) p += row[q * 64 + lane] * hs[q * 64 + lane];
      for (int off = 32; off > 0; off >>= 1) p += __shfl_down(p, off);
      if (lane == 0) ad[e] = fmaxf(p, 0.f);
    }
    __syncthreads();
    if (t < 64) {
      float v = ad[t];
      float rs = v;
      for (int off = 1; off < 64; off <<= 1) rs += __shfl_xor(rs, off);
      Dout[x * 64 + t] = f2bf_rne(v / fmaxf(rs, 1e-6f));
    }
  } else {
    int idx = (blockIdx.x - 64) * 256 + t;      // 0 .. 163839
    const float* src = (idx < 81920) ? T1 : T2;
    unsigned short* dst = (idx < 81920) ? T1T : T2T;
    int o = (idx < 81920) ? idx : idx - 81920;
    int g = o >> 14;
    int r = o & 16383;
    int h = r >> 7;      // out row = n index
    int f = r & 127;     // out col = k index
    dst[o] = f2bf_rne(src[g * 16384 + f * 128 + h]);
  }
}

// ---------------- main: per (g,b): out = elu(D @ elu(mu@T1) @ T2) ----------
// Block handles NB=4 consecutive b for one g; 4 waves; wave w owns n-block
// [32w,32w+32). T1/T2/D fragments hoisted to regs once per block. mu staging
// double-buffered: loads for it+1 issued at iter top (pinned by
// sched_barrier(0)), LDS-written late; latency hides under GEMM1+GEMM2.
// GEMM2 computed transposed (h2^T = h1^T @ D^T, same D frags as B-operand) so
// its C-frag has 4 consecutive h per lane -> h2 scatter is b64 writes.
// LDS 48KB: buf0/buf1 (mu, h2-aliased) + s_h1.
__launch_bounds__(256, 2)
__global__ void k_main(const float* __restrict__ mu,
                       const unsigned short* __restrict__ Dm,
                       const unsigned short* __restrict__ T1T,
                       const unsigned short* __restrict__ T2T,
                       float* __restrict__ out) {
  __shared__ __align__(16) char smem[49152];
  char* s_h1 = smem + 32768;   // 16KB [128 h][64 e] swz

  const int g = blockIdx.y, b0 = blockIdx.x * 4;
  const int t = threadIdx.x;
  const int lane = t & 63, w = t >> 6;
  const int l15 = lane & 15, lk = lane >> 4;
  const int nb = w * 32;

  // ---- hoist T1/T2/D fragments into registers (loop-invariant) ----
  const unsigned short* t1g = T1T + g * 16384;
  const unsigned short* t2g = T2T + g * 16384;
  bf16x8 tb0[4], tb1[4], t2b0[4], t2b1[4];
  #pragma unroll
  for (int kc = 0; kc < 4; ++kc) {
    int k0 = kc * 32 + lk * 8;
    tb0[kc]  = *(const bf16x8*)(const void*)(t1g + (nb + l15) * 128 + k0);
    tb1[kc]  = *(const bf16x8*)(const void*)(t1g + (nb + 16 + l15) * 128 + k0);
    t2b0[kc] = *(const bf16x8*)(const void*)(t2g + (nb + l15) * 128 + k0);
    t2b1[kc] = *(const bf16x8*)(const void*)(t2g + (nb + 16 + l15) * 128 + k0);
  }
  bf16x8 aDf[4][2];   // B-frag for GEMM2': rows x = np*16+l15 of D, k=e
  #pragma unroll
  for (int np = 0; np < 4; ++np)
    #pragma unroll
    for (int kc = 0; kc < 2; ++kc)
      aDf[np][kc] = *(const bf16x8*)(const void*)(Dm + (np * 16 + l15) * 64 + kc * 32 + lk * 8);

  // ---- prologue: stage mu for it=0 into buf0 ----
  {
    const float4v* src = (const float4v*)(mu + (size_t)(g * 1024 + b0) * 8192);
    #pragma unroll
    for (int k = 0; k < 8; ++k) {
      int q = t + k * 256;
      float4v v = src[q];
      int row = q >> 5, col4 = (q & 31) * 4;
      ushort4v u;
      u[0] = f2bf(v[0]); u[1] = f2bf(v[1]); u[2] = f2bf(v[2]); u[3] = f2bf(v[3]);
      *(ushort4v*)(smem + ((row * 256 + col4 * 2) ^ ((row & 7) << 4))) = u;
    }
  }
  __syncthreads();

  #pragma unroll 1
  for (int it = 0; it < 4; ++it) {
    char* bcur = smem + ((it & 1) << 14);
    char* bnxt = smem + (((it + 1) & 1) << 14);
    const bool pre = (it < 3);

    // issue next-iter mu loads; pin them here so hipcc can't sink them
    float4v vn[8];
    if (pre) {
      const float4v* srcn = (const float4v*)(mu + (size_t)(g * 1024 + b0 + it + 1) * 8192);
      #pragma unroll
      for (int k = 0; k < 8; ++k) vn[k] = srcn[t + k * 256];
      __builtin_amdgcn_sched_barrier(0);
    }

    // ---- GEMM1: h1 = elu(mu @ T1); write h1^T[h][e] to s_h1 (wave-local cols)
    f32x4 acc[4][2];
    #pragma unroll
    for (int m = 0; m < 4; ++m) { acc[m][0] = (f32x4){0,0,0,0}; acc[m][1] = (f32x4){0,0,0,0}; }
    #pragma unroll
    for (int kc = 0; kc < 4; ++kc) {
      int k0 = kc * 32 + lk * 8;
      #pragma unroll
      for (int m = 0; m < 4; ++m) {
        int row = m * 16 + l15;
        bf16x8 a = *(const bf16x8*)(bcur + ((row * 256 + k0 * 2) ^ ((row & 7) << 4)));
        acc[m][0] = __builtin_amdgcn_mfma_f32_16x16x32_bf16(a, tb0[kc], acc[m][0], 0, 0, 0);
        acc[m][1] = __builtin_amdgcn_mfma_f32_16x16x32_bf16(a, tb1[kc], acc[m][1], 0, 0, 0);
      }
    }
    #pragma unroll
    for (int m = 0; m < 4; ++m)
      #pragma unroll
      for (int n = 0; n < 2; ++n) {
        int col = nb + n * 16 + l15;           // h
        int e0 = m * 16 + lk * 4;              // e base
        ushort4v u;
        u[0] = f2bf(eluf(acc[m][n][0]));
        u[1] = f2bf(eluf(acc[m][n][1]));
        u[2] = f2bf(eluf(acc[m][n][2]));
        u[3] = f2bf(eluf(acc[m][n][3]));
        *(ushort4v*)(s_h1 + ((col * 128 + e0 * 2) ^ ((col & 7) << 4))) = u;
      }
    __syncthreads();   // h1 ready; all GEMM1 mu reads done -> bcur reusable

    // ---- GEMM2': h2^T = h1^T @ D^T (M=h 128 rows: wave w owns [32w,32w+32))
    f32x4 acc2[2][4];
    #pragma unroll
    for (int mp = 0; mp < 2; ++mp)
      #pragma unroll
      for (int np = 0; np < 4; ++np) acc2[mp][np] = (f32x4){0,0,0,0};
    #pragma unroll
    for (int kc = 0; kc < 2; ++kc) {
      int e0 = kc * 32 + lk * 8;
      int hr0 = w * 32 + l15, hr1 = w * 32 + 16 + l15;
      bf16x8 a0 = *(const bf16x8*)(s_h1 + ((hr0 * 128 + e0 * 2) ^ ((hr0 & 7) << 4)));
      bf16x8 a1 = *(const bf16x8*)(s_h1 + ((hr1 * 128 + e0 * 2) ^ ((hr1 & 7) << 4)));
      #pragma unroll
      for (int np = 0; np < 4; ++np) {
        acc2[0][np] = __builtin_amdgcn_mfma_f32_16x16x32_bf16(a0, aDf[np][kc], acc2[0][np], 0, 0, 0);
        acc2[1][np] = __builtin_amdgcn_mfma_f32_16x16x32_bf16(a1, aDf[np][kc], acc2[1][np], 0, 0, 0);
      }
    }
    // write h2[x][h] into bcur (b64 per frag: 4 consecutive h at fixed x)
    #pragma unroll
    for (int mp = 0; mp < 2; ++mp)
      #pragma unroll
      for (int np = 0; np < 4; ++np) {
        int x = np * 16 + l15;
        int h0 = w * 32 + mp * 16 + lk * 4;
        ushort4v u;
        u[0] = f2bf(acc2[mp][np][0]);
        u[1] = f2bf(acc2[mp][np][1]);
        u[2] = f2bf(acc2[mp][np][2]);
        u[3] = f2bf(acc2[mp][np][3]);
        *(ushort4v*)(bcur + ((x * 256 + h0 * 2) ^ ((x & 7) << 4))) = u;
      }
    // stage mu_{it+1} -> bnxt (waitcnt for vn lands here, covered by G1+G2)
    if (pre) {
      #pragma unroll
      for (int k = 0; k < 8; ++k) {
        int q = t + k * 256;
        int row = q >> 5, col4 = (q & 31) * 4;
        ushort4v u;
        u[0] = f2bf(vn[k][0]); u[1] = f2bf(vn[k][1]);
        u[2] = f2bf(vn[k][2]); u[3] = f2bf(vn[k][3]);
        *(ushort4v*)(bnxt + ((row * 256 + col4 * 2) ^ ((row & 7) << 4))) = u;
      }
    }
    __syncthreads();   // h2 + mu_next visible

    // ---- GEMM3: out = elu(h2 @ T2) ----
    f32x4 acc3[4][2];
    #pragma unroll
    for (int m = 0; m < 4; ++m) { acc3[m][0] = (f32x4){0,0,0,0}; acc3[m][1] = (f32x4){0,0,0,0}; }
    #pragma unroll
    for (int kc = 0; kc < 4; ++kc) {
      int k0 = kc * 32 + lk * 8;
      #pragma unroll
      for (int m = 0; m < 4; ++m) {
        int row = m * 16 + l15;
        bf16x8 a = *(const bf16x8*)(bcur + ((row * 256 + k0 * 2) ^ ((row & 7) << 4)));
        acc3[m][0] = __builtin_amdgcn_mfma_f32_16x16x32_bf16(a, t2b0[kc], acc3[m][0], 0, 0, 0);
        acc3[m][1] = __builtin_amdgcn_mfma_f32_16x16x32_bf16(a, t2b1[kc], acc3[m][1], 0, 0, 0);
      }
    }
    float* ob = out + (size_t)(g * 1024 + b0 + it) * 8192;
    #pragma unroll
    for (int m = 0; m < 4; ++m)
      #pragma unroll
      for (int n = 0; n < 2; ++n) {
        int f = nb + n * 16 + l15;
        #pragma unroll
        for (int r = 0; r < 4; ++r) {
          int e = m * 16 + lk * 4 + r;
          ob[e * 128 + f] = eluf(acc3[m][n][r]);
        }
      }
  }
}

extern "C" void kernel_launch(void* const* d_in, const int* in_sizes, int n_in,
                              void* d_out, int out_size, void* d_ws, size_t ws_size,
                              hipStream_t stream) {
  const float* mu = (const float*)d_in[0];
  const float* A  = (const float*)d_in[1];
  const float* W1 = (const float*)d_in[2];
  const float* W2 = (const float*)d_in[3];
  const float* T1 = (const float*)d_in[4];
  const float* T2 = (const float*)d_in[5];
  float* out = (float*)d_out;

  char* ws = (char*)d_ws;
  float* hbuf          = (float*)ws;                     // 1 KB
  unsigned short* Dm   = (unsigned short*)(ws + 1024);   // 8 KB
  unsigned short* T1T  = (unsigned short*)(ws + 9216);   // 160 KB
  unsigned short* T2T  = (unsigned short*)(ws + 173056); // 160 KB

  hipLaunchKernelGGL(k_hidden, dim3(256), dim3(256), 0, stream, A, W1, hbuf);
  hipLaunchKernelGGL(k_pre2,   dim3(704), dim3(256), 0, stream, hbuf, W2, Dm, T1, T2, T1T, T2T);
  hipLaunchKernelGGL(k_main,   dim3(256, 5), dim3(256), 0, stream, mu, Dm, T1T, T2T, out);
}